// Round 2
// baseline (453.131 us; speedup 1.0000x reference)
//
#include <hip/hip_runtime.h>
#include <hip/hip_bf16.h>

typedef __attribute__((ext_vector_type(8))) short short8;
typedef __attribute__((ext_vector_type(4))) short short4v;
typedef __attribute__((ext_vector_type(4))) float f32x4;
typedef __attribute__((ext_vector_type(4))) float float4v;

#define DEVI static __device__ __forceinline__

DEVI unsigned short f2bf(float f) {
    union { float f; unsigned int u; } v; v.f = f;
    unsigned int r = v.u + 0x7fffu + ((v.u >> 16) & 1u);
    return (unsigned short)(r >> 16);
}

static constexpr int LSEQ = 2048;
static constexpr int NH = 16;
static constexpr int EH = 64;

// ---------- weight convert + transpose: W[k][n] f32 -> Wt[n][k] bf16 ----------
__global__ __launch_bounds__(256) void wconv_kernel(
    const float* __restrict__ W0, const float* __restrict__ W1,
    const float* __restrict__ W2, const float* __restrict__ W3,
    unsigned short* __restrict__ T0, unsigned short* __restrict__ T1,
    unsigned short* __restrict__ T2, unsigned short* __restrict__ T3)
{
    __shared__ unsigned short t[64][72];
    const float* W; unsigned short* T;
    switch (blockIdx.y) {
        case 0:  W = W0; T = T0; break;
        case 1:  W = W1; T = T1; break;
        case 2:  W = W2; T = T2; break;
        default: W = W3; T = T3; break;
    }
    const int bx = blockIdx.x & 15;   // n tile
    const int by = blockIdx.x >> 4;   // k tile
    const int tid = threadIdx.x;
    #pragma unroll
    for (int i = 0; i < 16; ++i) {
        int idx = tid + i * 256;
        int kk = idx >> 6, nn = idx & 63;
        t[nn][kk] = f2bf(W[(size_t)(by * 64 + kk) * 1024 + bx * 64 + nn]);
    }
    __syncthreads();
    #pragma unroll
    for (int i = 0; i < 16; ++i) {
        int idx = tid + i * 256;
        int nn = idx >> 6, kk = idx & 63;
        T[(size_t)(bx * 64 + nn) * 1024 + by * 64 + kk] = t[nn][kk];
    }
}

// ---------- GEMM: C[8192,1024] = A[8192,1024] @ Wt^T + bias ----------
// Wt is [n][k] bf16 (pre-transposed). A is fp32 (converted on stage) or bf16.
// OUT_QKV: write bf16 to [B,H,L,E]; else write fp32 row-major [8192,1024].
template<bool A_BF16, bool OUT_QKV>
__global__ __launch_bounds__(256) void gemm_kernel(
    const void* __restrict__ Ap,
    const unsigned short* __restrict__ Wt,
    const float* __restrict__ bias,
    void* __restrict__ Out)
{
    __shared__ short As[4][128][8];  // [k/8][row][k%8]
    __shared__ short Bs[4][128][8];  // [k/8][n][k%8]
    const int tid = threadIdx.x;
    const int lane = tid & 63;
    const int wave = tid >> 6;
    const int wr = wave >> 1, wc = wave & 1;
    const int g = lane >> 4, lr = lane & 15;
    const int row0 = blockIdx.x * 128;
    const int col0 = blockIdx.y * 128;

    f32x4 acc[4][4] = {};

    for (int k0 = 0; k0 < 1024; k0 += 32) {
        if constexpr (!A_BF16) {
            const float* A = (const float*)Ap;
            #pragma unroll
            for (int i = 0; i < 4; ++i) {
                int c = tid + i * 256;
                int r = c >> 3, k4 = c & 7;
                float4v v = *(const float4v*)(A + (size_t)(row0 + r) * 1024 + k0 + k4 * 4);
                short4v b;
                b[0] = (short)f2bf(v[0]); b[1] = (short)f2bf(v[1]);
                b[2] = (short)f2bf(v[2]); b[3] = (short)f2bf(v[3]);
                *(short4v*)(&As[k4 >> 1][r][(k4 & 1) * 4]) = b;
            }
        } else {
            const unsigned short* A = (const unsigned short*)Ap;
            #pragma unroll
            for (int i = 0; i < 2; ++i) {
                int c = tid + i * 256;
                int r = c >> 2, kq = c & 3;
                short8 vv = *(const short8*)(A + (size_t)(row0 + r) * 1024 + k0 + kq * 8);
                *(short8*)(&As[kq][r][0]) = vv;
            }
        }
        {
            #pragma unroll
            for (int i = 0; i < 2; ++i) {
                int c = tid + i * 256;
                int r = c >> 2, kq = c & 3;
                short8 vv = *(const short8*)(Wt + (size_t)(col0 + r) * 1024 + k0 + kq * 8);
                *(short8*)(&Bs[kq][r][0]) = vv;
            }
        }
        __syncthreads();
        short8 af[4], bfr[4];
        #pragma unroll
        for (int m = 0; m < 4; ++m)
            af[m] = *(const short8*)(&As[g][wr * 64 + m * 16 + lr][0]);
        #pragma unroll
        for (int n = 0; n < 4; ++n)
            bfr[n] = *(const short8*)(&Bs[g][wc * 64 + n * 16 + lr][0]);
        #pragma unroll
        for (int m = 0; m < 4; ++m)
            #pragma unroll
            for (int n = 0; n < 4; ++n)
                acc[m][n] = __builtin_amdgcn_mfma_f32_16x16x32_bf16(af[m], bfr[n], acc[m][n], 0, 0, 0);
        __syncthreads();
    }

    #pragma unroll
    for (int m = 0; m < 4; ++m) {
        const int row_g = row0 + wr * 64 + m * 16 + g * 4;
        #pragma unroll
        for (int n = 0; n < 4; ++n) {
            const int col_g = col0 + wc * 64 + n * 16 + lr;
            const float bv = bias[col_g];
            #pragma unroll
            for (int r = 0; r < 4; ++r) {
                const float val = acc[m][n][r] + bv;
                const int rg = row_g + r;
                if constexpr (OUT_QKV) {
                    const int b = rg >> 11, l = rg & 2047;
                    const int h = col_g >> 6, e = col_g & 63;
                    ((unsigned short*)Out)[(((size_t)(b * NH + h)) * LSEQ + l) * EH + e] = f2bf(val);
                } else {
                    ((float*)Out)[(size_t)rg * 1024 + col_g] = val;
                }
            }
        }
    }
}

// ---------- flash attention: Q,K,V bf16 [BH][2048][64] -> Oa bf16 [8192][1024] ----------
// Output uses the reference's "mix" layout:
//   attn(b,h,l,d) -> row = b*2048 + h*128 + (l>>4), col = (l&15)*64 + d
__global__ __launch_bounds__(256) void flash_kernel(
    const unsigned short* __restrict__ Q,
    const unsigned short* __restrict__ K,
    const unsigned short* __restrict__ V,
    unsigned short* __restrict__ Oa)
{
    __shared__ short vt[8][64][8];     // V^T tile: [kk/8][e][kk%8]
    __shared__ short ps[4][8][16][8];  // per-wave P: [wave][kk/8][q][kk%8]
    const int tid = threadIdx.x, lane = tid & 63, wave = tid >> 6;
    const int g = lane >> 4, lr = lane & 15;
    const int bh = blockIdx.x;
    const int q0 = blockIdx.y * 64 + wave * 16;
    const size_t base = (size_t)bh * LSEQ * EH;

    short8 qf[2];
    #pragma unroll
    for (int j = 0; j < 2; ++j)
        qf[j] = *(const short8*)(Q + base + (size_t)(q0 + lr) * EH + j * 32 + g * 8);

    f32x4 o[4] = {};
    float m_[4], l_[4];
    #pragma unroll
    for (int r = 0; r < 4; ++r) { m_[r] = -1e30f; l_[r] = 0.f; }

    const float CEXP = 0.125f * 1.44269504088896f;  // scale * log2(e)

    for (int kt = 0; kt < LSEQ; kt += 64) {
        __syncthreads();
        // stage V^T
        {
            const int s = tid >> 2;
            const int e16 = (tid & 3) * 16;
            short8 v0 = *(const short8*)(V + base + (size_t)(kt + s) * EH + e16);
            short8 v1 = *(const short8*)(V + base + (size_t)(kt + s) * EH + e16 + 8);
            const int kg = s >> 3, ke = s & 7;
            #pragma unroll
            for (int jj = 0; jj < 8; ++jj) vt[kg][e16 + jj][ke] = v0[jj];
            #pragma unroll
            for (int jj = 0; jj < 8; ++jj) vt[kg][e16 + 8 + jj][ke] = v1[jj];
        }
        __syncthreads();

        // scores S[q, kk] for kk-tile of 64
        f32x4 sc[4];
        #pragma unroll
        for (int kb = 0; kb < 4; ++kb) {
            short8 kf0 = *(const short8*)(K + base + (size_t)(kt + kb * 16 + lr) * EH + g * 8);
            short8 kf1 = *(const short8*)(K + base + (size_t)(kt + kb * 16 + lr) * EH + 32 + g * 8);
            f32x4 z = {};
            z = __builtin_amdgcn_mfma_f32_16x16x32_bf16(qf[0], kf0, z, 0, 0, 0);
            sc[kb] = __builtin_amdgcn_mfma_f32_16x16x32_bf16(qf[1], kf1, z, 0, 0, 0);
        }

        // online softmax (rows owned by this lane: g*4 + r)
        float rmax[4];
        #pragma unroll
        for (int r = 0; r < 4; ++r)
            rmax[r] = fmaxf(fmaxf(sc[0][r], sc[1][r]), fmaxf(sc[2][r], sc[3][r]));
        #pragma unroll
        for (int msk = 1; msk <= 8; msk <<= 1) {
            #pragma unroll
            for (int r = 0; r < 4; ++r)
                rmax[r] = fmaxf(rmax[r], __shfl_xor(rmax[r], msk));
        }
        float al[4], psum[4];
        #pragma unroll
        for (int r = 0; r < 4; ++r) {
            const float mn = fmaxf(m_[r], rmax[r]);
            al[r] = exp2f((m_[r] - mn) * CEXP);
            m_[r] = mn;
            psum[r] = 0.f;
        }
        #pragma unroll
        for (int kb = 0; kb < 4; ++kb) {
            const int kg = (kb * 16 + lr) >> 3, ke = lr & 7;
            #pragma unroll
            for (int r = 0; r < 4; ++r) {
                const float p = exp2f((sc[kb][r] - m_[r]) * CEXP);
                psum[r] += p;
                ps[wave][kg][g * 4 + r][ke] = (short)f2bf(p);
            }
        }
        #pragma unroll
        for (int msk = 1; msk <= 8; msk <<= 1) {
            #pragma unroll
            for (int r = 0; r < 4; ++r)
                psum[r] += __shfl_xor(psum[r], msk);
        }
        #pragma unroll
        for (int r = 0; r < 4; ++r)
            l_[r] = l_[r] * al[r] + psum[r];
        #pragma unroll
        for (int n = 0; n < 4; ++n)
            #pragma unroll
            for (int r = 0; r < 4; ++r)
                o[n][r] *= al[r];

        // PV
        #pragma unroll
        for (int k2 = 0; k2 < 2; ++k2) {
            short8 pa = *(const short8*)(&ps[wave][k2 * 4 + g][lr][0]);
            #pragma unroll
            for (int n = 0; n < 4; ++n) {
                short8 vf = *(const short8*)(&vt[k2 * 4 + g][n * 16 + lr][0]);
                o[n] = __builtin_amdgcn_mfma_f32_16x16x32_bf16(pa, vf, o[n], 0, 0, 0);
            }
        }
    }

    // epilogue, "mix" layout: all 16 q-rows of this wave share one output row.
    // l = q0 + g*4 + r (q0 16-aligned) => row = b*2048 + h*128 + (q0>>4),
    // col = (g*4+r)*64 + (n*16+lr)
    const int b = bh >> 4, h = bh & 15;
    const size_t orow = (size_t)(b * LSEQ + h * 128 + (q0 >> 4));
    #pragma unroll
    for (int n = 0; n < 4; ++n) {
        #pragma unroll
        for (int r = 0; r < 4; ++r) {
            Oa[orow * 1024 + (g * 4 + r) * 64 + n * 16 + lr] = f2bf(o[n][r] / l_[r]);
        }
    }
}

extern "C" void kernel_launch(void* const* d_in, const int* in_sizes, int n_in,
                              void* d_out, int out_size, void* d_ws, size_t ws_size,
                              hipStream_t stream) {
    (void)in_sizes; (void)n_in; (void)out_size; (void)ws_size;
    const float* q  = (const float*)d_in[0];
    const float* k  = (const float*)d_in[1];
    const float* v  = (const float*)d_in[2];
    const float* Wq = (const float*)d_in[3];
    const float* bq = (const float*)d_in[4];
    const float* Wk = (const float*)d_in[5];
    const float* bk = (const float*)d_in[6];
    const float* Wv = (const float*)d_in[7];
    const float* bv = (const float*)d_in[8];
    const float* Wo = (const float*)d_in[9];
    const float* bo = (const float*)d_in[10];

    char* ws = (char*)d_ws;
    const size_t WT = (size_t)1 << 21;   // 2MB per transposed weight
    const size_t QK = (size_t)1 << 24;   // 16MB per bf16 [8192][1024] buffer
    unsigned short* wt_q = (unsigned short*)(ws);
    unsigned short* wt_k = (unsigned short*)(ws + WT);
    unsigned short* wt_v = (unsigned short*)(ws + 2 * WT);
    unsigned short* wt_o = (unsigned short*)(ws + 3 * WT);
    unsigned short* qb   = (unsigned short*)(ws + 4 * WT);        // 16MB in ws
    unsigned short* ab   = (unsigned short*)(ws + 4 * WT + QK);   // 16MB in ws (total ws use: 40MB)
    // K/V bf16 intermediates live in d_out (32MB fp32 buffer, fully
    // overwritten by the final GEMM afterwards -> deterministic).
    unsigned short* kb_  = (unsigned short*)d_out;
    unsigned short* vb   = (unsigned short*)((char*)d_out + QK);

    wconv_kernel<<<dim3(256, 4), 256, 0, stream>>>(Wq, Wk, Wv, Wo, wt_q, wt_k, wt_v, wt_o);
    gemm_kernel<false, true><<<dim3(64, 8), 256, 0, stream>>>(q, wt_q, bq, qb);
    gemm_kernel<false, true><<<dim3(64, 8), 256, 0, stream>>>(k, wt_k, bk, kb_);
    gemm_kernel<false, true><<<dim3(64, 8), 256, 0, stream>>>(v, wt_v, bv, vb);
    flash_kernel<<<dim3(64, 32), 256, 0, stream>>>(qb, kb_, vb, ab);
    gemm_kernel<true, false><<<dim3(64, 8), 256, 0, stream>>>(ab, wt_o, bo, (float*)d_out);
}

// Round 3
// 451.838 us; speedup vs baseline: 1.0029x; 1.0029x over previous
//
#include <hip/hip_runtime.h>
#include <hip/hip_bf16.h>

typedef __attribute__((ext_vector_type(8))) short short8;
typedef __attribute__((ext_vector_type(4))) short short4v;
typedef __attribute__((ext_vector_type(4))) float f32x4;
typedef __attribute__((ext_vector_type(16))) float f32x16;
typedef __attribute__((ext_vector_type(4))) float float4v;

#define DEVI static __device__ __forceinline__

DEVI unsigned short f2bf(float f) {
    union { float f; unsigned int u; } v; v.f = f;
    unsigned int r = v.u + 0x7fffu + ((v.u >> 16) & 1u);
    return (unsigned short)(r >> 16);
}

DEVI unsigned int pkbf(float a, float b) {
    return (unsigned int)f2bf(a) | ((unsigned int)f2bf(b) << 16);
}

static constexpr int LSEQ = 2048;
static constexpr int NH = 16;
static constexpr int EH = 64;

// ---------- weight convert + transpose: W[k][n] f32 -> Wt[n][k] bf16 ----------
__global__ __launch_bounds__(256) void wconv_kernel(
    const float* __restrict__ W0, const float* __restrict__ W1,
    const float* __restrict__ W2, const float* __restrict__ W3,
    unsigned short* __restrict__ T0, unsigned short* __restrict__ T1,
    unsigned short* __restrict__ T2, unsigned short* __restrict__ T3)
{
    __shared__ unsigned short t[64][72];
    const float* W; unsigned short* T;
    switch (blockIdx.y) {
        case 0:  W = W0; T = T0; break;
        case 1:  W = W1; T = T1; break;
        case 2:  W = W2; T = T2; break;
        default: W = W3; T = T3; break;
    }
    const int bx = blockIdx.x & 15;   // n tile
    const int by = blockIdx.x >> 4;   // k tile
    const int tid = threadIdx.x;
    #pragma unroll
    for (int i = 0; i < 16; ++i) {
        int idx = tid + i * 256;
        int kk = idx >> 6, nn = idx & 63;
        t[nn][kk] = f2bf(W[(size_t)(by * 64 + kk) * 1024 + bx * 64 + nn]);
    }
    __syncthreads();
    #pragma unroll
    for (int i = 0; i < 16; ++i) {
        int idx = tid + i * 256;
        int nn = idx >> 6, kk = idx & 63;
        T[(size_t)(bx * 64 + nn) * 1024 + by * 64 + kk] = t[nn][kk];
    }
}

// ---------- GEMM: C[8192,1024] = A[8192,1024] @ Wt^T + bias ----------
template<bool A_BF16, bool OUT_QKV>
__global__ __launch_bounds__(256) void gemm_kernel(
    const void* __restrict__ Ap,
    const unsigned short* __restrict__ Wt,
    const float* __restrict__ bias,
    void* __restrict__ Out)
{
    __shared__ short As[4][128][8];  // [k/8][row][k%8]
    __shared__ short Bs[4][128][8];  // [k/8][n][k%8]
    const int tid = threadIdx.x;
    const int lane = tid & 63;
    const int wave = tid >> 6;
    const int wr = wave >> 1, wc = wave & 1;
    const int g = lane >> 4, lr = lane & 15;
    const int row0 = blockIdx.x * 128;
    const int col0 = blockIdx.y * 128;

    f32x4 acc[4][4] = {};

    for (int k0 = 0; k0 < 1024; k0 += 32) {
        if constexpr (!A_BF16) {
            const float* A = (const float*)Ap;
            #pragma unroll
            for (int i = 0; i < 4; ++i) {
                int c = tid + i * 256;
                int r = c >> 3, k4 = c & 7;
                float4v v = *(const float4v*)(A + (size_t)(row0 + r) * 1024 + k0 + k4 * 4);
                short4v b;
                b[0] = (short)f2bf(v[0]); b[1] = (short)f2bf(v[1]);
                b[2] = (short)f2bf(v[2]); b[3] = (short)f2bf(v[3]);
                *(short4v*)(&As[k4 >> 1][r][(k4 & 1) * 4]) = b;
            }
        } else {
            const unsigned short* A = (const unsigned short*)Ap;
            #pragma unroll
            for (int i = 0; i < 2; ++i) {
                int c = tid + i * 256;
                int r = c >> 2, kq = c & 3;
                short8 vv = *(const short8*)(A + (size_t)(row0 + r) * 1024 + k0 + kq * 8);
                *(short8*)(&As[kq][r][0]) = vv;
            }
        }
        {
            #pragma unroll
            for (int i = 0; i < 2; ++i) {
                int c = tid + i * 256;
                int r = c >> 2, kq = c & 3;
                short8 vv = *(const short8*)(Wt + (size_t)(col0 + r) * 1024 + k0 + kq * 8);
                *(short8*)(&Bs[kq][r][0]) = vv;
            }
        }
        __syncthreads();
        short8 af[4], bfr[4];
        #pragma unroll
        for (int m = 0; m < 4; ++m)
            af[m] = *(const short8*)(&As[g][wr * 64 + m * 16 + lr][0]);
        #pragma unroll
        for (int n = 0; n < 4; ++n)
            bfr[n] = *(const short8*)(&Bs[g][wc * 64 + n * 16 + lr][0]);
        #pragma unroll
        for (int m = 0; m < 4; ++m)
            #pragma unroll
            for (int n = 0; n < 4; ++n)
                acc[m][n] = __builtin_amdgcn_mfma_f32_16x16x32_bf16(af[m], bfr[n], acc[m][n], 0, 0, 0);
        __syncthreads();
    }

    #pragma unroll
    for (int m = 0; m < 4; ++m) {
        const int row_g = row0 + wr * 64 + m * 16 + g * 4;
        #pragma unroll
        for (int n = 0; n < 4; ++n) {
            const int col_g = col0 + wc * 64 + n * 16 + lr;
            const float bv = bias[col_g];
            #pragma unroll
            for (int r = 0; r < 4; ++r) {
                const float val = acc[m][n][r] + bv;
                const int rg = row_g + r;
                if constexpr (OUT_QKV) {
                    const int b = rg >> 11, l = rg & 2047;
                    const int h = col_g >> 6, e = col_g & 63;
                    ((unsigned short*)Out)[(((size_t)(b * NH + h)) * LSEQ + l) * EH + e] = f2bf(val);
                } else {
                    ((float*)Out)[(size_t)rg * 1024 + col_g] = val;
                }
            }
        }
    }
}

// ---------- V transpose: V [bh][2048][64] -> VT [bh][64][2048] ----------
__global__ __launch_bounds__(256) void vtrans_kernel(
    const unsigned short* __restrict__ V, unsigned short* __restrict__ VT)
{
    __shared__ unsigned short t[64][66];
    const int bh = blockIdx.x >> 5;
    const int l0 = (blockIdx.x & 31) * 64;
    const int tid = threadIdx.x;
    const int i = tid >> 2, c = (tid & 3) * 16;
    const unsigned short* src = V + (size_t)bh * LSEQ * EH + (size_t)(l0 + i) * EH + c;
    short8 x0 = *(const short8*)(src);
    short8 x1 = *(const short8*)(src + 8);
    #pragma unroll
    for (int j = 0; j < 8; ++j) t[i][c + j] = (unsigned short)x0[j];
    #pragma unroll
    for (int j = 0; j < 8; ++j) t[i][c + 8 + j] = (unsigned short)x1[j];
    __syncthreads();
    const int e = tid >> 2, j0 = (tid & 3) * 16;
    short8 y0, y1;
    #pragma unroll
    for (int j = 0; j < 8; ++j) y0[j] = (short)t[j0 + j][e];
    #pragma unroll
    for (int j = 0; j < 8; ++j) y1[j] = (short)t[j0 + 8 + j][e];
    unsigned short* dst = VT + (size_t)bh * EH * LSEQ + (size_t)e * LSEQ + l0 + j0;
    *(short8*)(dst) = y0;
    *(short8*)(dst + 8) = y1;
}

// ---------- P fragment assembly (C-layout -> B-frag layout, in-register) ----
DEVI short8 mk8(unsigned int w0, unsigned int w1, unsigned int w2, unsigned int w3) {
    union { unsigned int u[4]; short8 v; } x;
    x.u[0] = w0; x.u[1] = w1; x.u[2] = w2; x.u[3] = w3;
    return x.v;
}

// p holds S^T block values: reg r -> kv_local = (r&3) + 8*(r>>2) + 4*h.
// Produces B-frags for kv steps [0,16) (f0) and [16,32) (f1): lane needs
// kv = 16*s + 8*h + j, j=0..7.
DEVI void packP(const f32x16& p, int h, short8& f0, short8& f1) {
    unsigned int A0 = pkbf(p[0], p[1]),  A1 = pkbf(p[2], p[3]);
    unsigned int B0 = pkbf(p[4], p[5]),  B1 = pkbf(p[6], p[7]);
    unsigned int C0 = pkbf(p[8], p[9]),  C1 = pkbf(p[10], p[11]);
    unsigned int D0 = pkbf(p[12], p[13]), D1 = pkbf(p[14], p[15]);
    unsigned int t0 = __shfl_xor(h ? A0 : B0, 32);
    unsigned int t1 = __shfl_xor(h ? A1 : B1, 32);
    unsigned int t2 = __shfl_xor(h ? C0 : D0, 32);
    unsigned int t3 = __shfl_xor(h ? C1 : D1, 32);
    f0 = mk8(h ? t0 : A0, h ? t1 : A1, h ? B0 : t0, h ? B1 : t1);
    f1 = mk8(h ? t2 : C0, h ? t3 : C1, h ? D0 : t2, h ? D1 : t3);
}

// ---------- flash attention, LDS-free, swapped operands ----------
// Q,K bf16 [bh][2048][64]; VT bf16 [bh][64][2048]; out "mix" layout bf16 [8192][1024].
__global__ __launch_bounds__(256, 2) void flash2_kernel(
    const unsigned short* __restrict__ Q,
    const unsigned short* __restrict__ K,
    const unsigned short* __restrict__ VT,
    unsigned short* __restrict__ Oa)
{
    const int tid = threadIdx.x, lane = tid & 63, wave = tid >> 6;
    const int h = lane >> 5, ql = lane & 31;
    // XCD-clustering swizzle: all 16 q-tiles of one bh land on one XCD.
    const int bid = blockIdx.x;
    const int bh = (bid & 7) | ((bid >> 7) << 3);
    const int qt = (bid >> 3) & 15;
    const int q0 = qt * 128 + wave * 32;
    const unsigned short* Qb = Q + (size_t)bh * LSEQ * EH;
    const unsigned short* Kb = K + (size_t)bh * LSEQ * EH;
    const unsigned short* Vb = VT + (size_t)bh * EH * LSEQ;

    // Q B-frags: lane holds Q[q0+ql][e = 16s + 8h + j]
    short8 qf[4];
    #pragma unroll
    for (int s = 0; s < 4; ++s)
        qf[s] = *(const short8*)(Qb + (size_t)(q0 + ql) * EH + s * 16 + h * 8);

    f32x16 o0 = {}, o1 = {};   // O^T accs: e-blocks [0,32), [32,64); col = q = ql
    float m_ = -1e30f, l_ = 0.f;
    const float CEXP = 0.125f * 1.44269504088896f;  // scale * log2(e)

    for (int kt = 0; kt < LSEQ; kt += 64) {
        __syncthreads();  // keep the block's 4 waves converged for L1 K/V reuse
        // S^T = K · Q^T : two 32-kv blocks
        f32x16 s0 = {}, s1 = {};
        #pragma unroll
        for (int s = 0; s < 4; ++s) {
            short8 k0 = *(const short8*)(Kb + (size_t)(kt + ql) * EH + s * 16 + h * 8);
            short8 k1 = *(const short8*)(Kb + (size_t)(kt + 32 + ql) * EH + s * 16 + h * 8);
            s0 = __builtin_amdgcn_mfma_f32_32x32x16_bf16(k0, qf[s], s0, 0, 0, 0);
            s1 = __builtin_amdgcn_mfma_f32_32x32x16_bf16(k1, qf[s], s1, 0, 0, 0);
        }
        // online softmax; lane owns q-row ql, halves combine via shfl_xor(32)
        float a[8];
        #pragma unroll
        for (int i = 0; i < 8; ++i)
            a[i] = fmaxf(fmaxf(s0[i], s0[i + 8]), fmaxf(s1[i], s1[i + 8]));
        #pragma unroll
        for (int i = 0; i < 4; ++i) a[i] = fmaxf(a[i], a[i + 4]);
        float mx = fmaxf(fmaxf(a[0], a[2]), fmaxf(a[1], a[3]));
        mx = fmaxf(mx, __shfl_xor(mx, 32));
        const float mn = fmaxf(m_, mx);
        const float al = exp2f((m_ - mn) * CEXP);
        m_ = mn;
        const float mc = mn * CEXP;
        #pragma unroll
        for (int i = 0; i < 16; ++i) {
            s0[i] = exp2f(s0[i] * CEXP - mc);
            s1[i] = exp2f(s1[i] * CEXP - mc);
        }
        float bsum[8];
        #pragma unroll
        for (int i = 0; i < 8; ++i)
            bsum[i] = (s0[i] + s0[i + 8]) + (s1[i] + s1[i + 8]);
        #pragma unroll
        for (int i = 0; i < 4; ++i) bsum[i] += bsum[i + 4];
        float sm = (bsum[0] + bsum[1]) + (bsum[2] + bsum[3]);
        sm += __shfl_xor(sm, 32);
        l_ = l_ * al + sm;

        // P -> bf16 B-frags (4 kv-steps of 16)
        short8 pf[4];
        packP(s0, h, pf[0], pf[1]);
        packP(s1, h, pf[2], pf[3]);

        #pragma unroll
        for (int i = 0; i < 16; ++i) { o0[i] *= al; o1[i] *= al; }

        // O^T += V^T · P
        #pragma unroll
        for (int t = 0; t < 4; ++t) {
            short8 v0 = *(const short8*)(Vb + (size_t)ql * LSEQ + kt + t * 16 + h * 8);
            short8 v1 = *(const short8*)(Vb + (size_t)(32 + ql) * LSEQ + kt + t * 16 + h * 8);
            o0 = __builtin_amdgcn_mfma_f32_32x32x16_bf16(v0, pf[t], o0, 0, 0, 0);
            o1 = __builtin_amdgcn_mfma_f32_32x32x16_bf16(v1, pf[t], o1, 0, 0, 0);
        }
    }

    // epilogue: mix layout. l_global = q0+ql; e = (r&3)+8*(r>>2)+4h (+32 for o1)
    const float inv = 1.0f / l_;
    const int b_ = bh >> 4, hd = bh & 15;
    unsigned short* orow = Oa + ((size_t)(b_ * LSEQ + hd * 128 + ((q0 + ql) >> 4)) << 10)
                             + (ql & 15) * 64;
    #pragma unroll
    for (int r = 0; r < 16; r += 2) {
        const int e0 = (r & 3) + 8 * (r >> 2) + 4 * h;
        *(unsigned int*)(orow + e0)      = pkbf(o0[r] * inv, o0[r + 1] * inv);
        *(unsigned int*)(orow + e0 + 32) = pkbf(o1[r] * inv, o1[r + 1] * inv);
    }
}

extern "C" void kernel_launch(void* const* d_in, const int* in_sizes, int n_in,
                              void* d_out, int out_size, void* d_ws, size_t ws_size,
                              hipStream_t stream) {
    (void)in_sizes; (void)n_in; (void)out_size; (void)ws_size;
    const float* q  = (const float*)d_in[0];
    const float* k  = (const float*)d_in[1];
    const float* v  = (const float*)d_in[2];
    const float* Wq = (const float*)d_in[3];
    const float* bq = (const float*)d_in[4];
    const float* Wk = (const float*)d_in[5];
    const float* bk = (const float*)d_in[6];
    const float* Wv = (const float*)d_in[7];
    const float* bv = (const float*)d_in[8];
    const float* Wo = (const float*)d_in[9];
    const float* bo = (const float*)d_in[10];

    char* ws = (char*)d_ws;
    const size_t WT = (size_t)1 << 21;   // 2MB per transposed weight
    const size_t QK = (size_t)1 << 24;   // 16MB per bf16 [8192][1024] buffer
    unsigned short* wt_q = (unsigned short*)(ws);
    unsigned short* wt_k = (unsigned short*)(ws + WT);
    unsigned short* wt_v = (unsigned short*)(ws + 2 * WT);
    unsigned short* wt_o = (unsigned short*)(ws + 3 * WT);
    unsigned short* qb   = (unsigned short*)(ws + 4 * WT);            // 16MB
    unsigned short* ab   = (unsigned short*)(ws + 4 * WT + QK);       // 16MB
    unsigned short* vt   = (unsigned short*)(ws + 4 * WT + 2 * QK);   // 16MB (ws total 56MB)
    // K/V bf16 intermediates live in d_out (32MB fp32 buffer, fully
    // overwritten by the final GEMM afterwards -> deterministic).
    unsigned short* kb_  = (unsigned short*)d_out;
    unsigned short* vb   = (unsigned short*)((char*)d_out + QK);

    wconv_kernel<<<dim3(256, 4), 256, 0, stream>>>(Wq, Wk, Wv, Wo, wt_q, wt_k, wt_v, wt_o);
    gemm_kernel<false, true><<<dim3(64, 8), 256, 0, stream>>>(q, wt_q, bq, qb);
    gemm_kernel<false, true><<<dim3(64, 8), 256, 0, stream>>>(k, wt_k, bk, kb_);
    gemm_kernel<false, true><<<dim3(64, 8), 256, 0, stream>>>(v, wt_v, bv, vb);
    vtrans_kernel<<<dim3(2048), 256, 0, stream>>>(vb, vt);
    flash2_kernel<<<dim3(1024), 256, 0, stream>>>(qb, kb_, vt, ab);
    gemm_kernel<true, false><<<dim3(64, 8), 256, 0, stream>>>(ab, wt_o, bo, (float*)d_out);
}

// Round 4
// 285.197 us; speedup vs baseline: 1.5888x; 1.5843x over previous
//
#include <hip/hip_runtime.h>
#include <hip/hip_bf16.h>

typedef __attribute__((ext_vector_type(8))) short short8;
typedef __attribute__((ext_vector_type(4))) short short4v;
typedef __attribute__((ext_vector_type(4))) float f32x4;
typedef __attribute__((ext_vector_type(16))) float f32x16;
typedef __attribute__((ext_vector_type(4))) float float4v;

#define DEVI static __device__ __forceinline__

DEVI unsigned short f2bf(float f) {
    union { float f; unsigned int u; } v; v.f = f;
    unsigned int r = v.u + 0x7fffu + ((v.u >> 16) & 1u);
    return (unsigned short)(r >> 16);
}

DEVI unsigned int cvtpk(float lo, float hi) {
    unsigned int r;
    asm("v_cvt_pk_bf16_f32 %0, %1, %2" : "=v"(r) : "v"(lo), "v"(hi));
    return r;
}

static constexpr int LSEQ = 2048;
static constexpr int NH = 16;
static constexpr int EH = 64;

// ---------- weight convert + transpose: W[k][n] f32 -> Wt[n][k] bf16 ----------
__global__ __launch_bounds__(256) void wconv_kernel(
    const float* __restrict__ W0, const float* __restrict__ W1,
    const float* __restrict__ W2, const float* __restrict__ W3,
    unsigned short* __restrict__ T0, unsigned short* __restrict__ T1,
    unsigned short* __restrict__ T2, unsigned short* __restrict__ T3)
{
    __shared__ unsigned short t[64][72];
    const float* W; unsigned short* T;
    switch (blockIdx.y) {
        case 0:  W = W0; T = T0; break;
        case 1:  W = W1; T = T1; break;
        case 2:  W = W2; T = T2; break;
        default: W = W3; T = T3; break;
    }
    const int bx = blockIdx.x & 15;   // n tile
    const int by = blockIdx.x >> 4;   // k tile
    const int tid = threadIdx.x;
    #pragma unroll
    for (int i = 0; i < 16; ++i) {
        int idx = tid + i * 256;
        int kk = idx >> 6, nn = idx & 63;
        t[nn][kk] = f2bf(W[(size_t)(by * 64 + kk) * 1024 + bx * 64 + nn]);
    }
    __syncthreads();
    #pragma unroll
    for (int i = 0; i < 16; ++i) {
        int idx = tid + i * 256;
        int nn = idx >> 6, kk = idx & 63;
        T[(size_t)(bx * 64 + nn) * 1024 + by * 64 + kk] = t[nn][kk];
    }
}

// ---------- GEMM: C[8192,1024] = A[8192,1024] @ Wt^T + bias ----------
template<bool A_BF16, bool OUT_QKV>
__global__ __launch_bounds__(256) void gemm_kernel(
    const void* __restrict__ Ap,
    const unsigned short* __restrict__ Wt,
    const float* __restrict__ bias,
    void* __restrict__ Out)
{
    __shared__ short As[4][128][8];  // [k/8][row][k%8]
    __shared__ short Bs[4][128][8];  // [k/8][n][k%8]
    const int tid = threadIdx.x;
    const int lane = tid & 63;
    const int wave = tid >> 6;
    const int wr = wave >> 1, wc = wave & 1;
    const int g = lane >> 4, lr = lane & 15;
    const int row0 = blockIdx.x * 128;
    const int col0 = blockIdx.y * 128;

    f32x4 acc[4][4] = {};

    for (int k0 = 0; k0 < 1024; k0 += 32) {
        if constexpr (!A_BF16) {
            const float* A = (const float*)Ap;
            #pragma unroll
            for (int i = 0; i < 4; ++i) {
                int c = tid + i * 256;
                int r = c >> 3, k4 = c & 7;
                float4v v = *(const float4v*)(A + (size_t)(row0 + r) * 1024 + k0 + k4 * 4);
                short4v b;
                b[0] = (short)f2bf(v[0]); b[1] = (short)f2bf(v[1]);
                b[2] = (short)f2bf(v[2]); b[3] = (short)f2bf(v[3]);
                *(short4v*)(&As[k4 >> 1][r][(k4 & 1) * 4]) = b;
            }
        } else {
            const unsigned short* A = (const unsigned short*)Ap;
            #pragma unroll
            for (int i = 0; i < 2; ++i) {
                int c = tid + i * 256;
                int r = c >> 2, kq = c & 3;
                short8 vv = *(const short8*)(A + (size_t)(row0 + r) * 1024 + k0 + kq * 8);
                *(short8*)(&As[kq][r][0]) = vv;
            }
        }
        {
            #pragma unroll
            for (int i = 0; i < 2; ++i) {
                int c = tid + i * 256;
                int r = c >> 2, kq = c & 3;
                short8 vv = *(const short8*)(Wt + (size_t)(col0 + r) * 1024 + k0 + kq * 8);
                *(short8*)(&Bs[kq][r][0]) = vv;
            }
        }
        __syncthreads();
        short8 af[4], bfr[4];
        #pragma unroll
        for (int m = 0; m < 4; ++m)
            af[m] = *(const short8*)(&As[g][wr * 64 + m * 16 + lr][0]);
        #pragma unroll
        for (int n = 0; n < 4; ++n)
            bfr[n] = *(const short8*)(&Bs[g][wc * 64 + n * 16 + lr][0]);
        #pragma unroll
        for (int m = 0; m < 4; ++m)
            #pragma unroll
            for (int n = 0; n < 4; ++n)
                acc[m][n] = __builtin_amdgcn_mfma_f32_16x16x32_bf16(af[m], bfr[n], acc[m][n], 0, 0, 0);
        __syncthreads();
    }

    #pragma unroll
    for (int m = 0; m < 4; ++m) {
        const int row_g = row0 + wr * 64 + m * 16 + g * 4;
        #pragma unroll
        for (int n = 0; n < 4; ++n) {
            const int col_g = col0 + wc * 64 + n * 16 + lr;
            const float bv = bias[col_g];
            #pragma unroll
            for (int r = 0; r < 4; ++r) {
                const float val = acc[m][n][r] + bv;
                const int rg = row_g + r;
                if constexpr (OUT_QKV) {
                    const int b = rg >> 11, l = rg & 2047;
                    const int h = col_g >> 6, e = col_g & 63;
                    ((unsigned short*)Out)[(((size_t)(b * NH + h)) * LSEQ + l) * EH + e] = f2bf(val);
                } else {
                    ((float*)Out)[(size_t)rg * 1024 + col_g] = val;
                }
            }
        }
    }
}

// ---------- V transpose: V [bh][2048][64] -> VT [bh][64][2048] ----------
__global__ __launch_bounds__(256) void vtrans_kernel(
    const unsigned short* __restrict__ V, unsigned short* __restrict__ VT)
{
    __shared__ unsigned short t[64][66];
    const int bh = blockIdx.x >> 5;
    const int l0 = (blockIdx.x & 31) * 64;
    const int tid = threadIdx.x;
    const int i = tid >> 2, c = (tid & 3) * 16;
    const unsigned short* src = V + (size_t)bh * LSEQ * EH + (size_t)(l0 + i) * EH + c;
    short8 x0 = *(const short8*)(src);
    short8 x1 = *(const short8*)(src + 8);
    #pragma unroll
    for (int j = 0; j < 8; ++j) t[i][c + j] = (unsigned short)x0[j];
    #pragma unroll
    for (int j = 0; j < 8; ++j) t[i][c + 8 + j] = (unsigned short)x1[j];
    __syncthreads();
    const int e = tid >> 2, j0 = (tid & 3) * 16;
    short8 y0, y1;
    #pragma unroll
    for (int j = 0; j < 8; ++j) y0[j] = (short)t[j0 + j][e];
    #pragma unroll
    for (int j = 0; j < 8; ++j) y1[j] = (short)t[j0 + 8 + j][e];
    unsigned short* dst = VT + (size_t)bh * EH * LSEQ + (size_t)e * LSEQ + l0 + j0;
    *(short8*)(dst) = y0;
    *(short8*)(dst + 8) = y1;
}

// ---------- P fragment assembly (C-layout -> B-frag layout, in-register) ----
DEVI short8 mk8(unsigned int w0, unsigned int w1, unsigned int w2, unsigned int w3) {
    union { unsigned int u[4]; short8 v; } x;
    x.u[0] = w0; x.u[1] = w1; x.u[2] = w2; x.u[3] = w3;
    return x.v;
}

// p holds S^T block values: reg r -> kv_local = (r&3) + 8*(r>>2) + 4*h.
// Produces B-frags for kv steps [0,16) (f0) and [16,32) (f1).
DEVI void packP(const f32x16& p, int h, short8& f0, short8& f1) {
    unsigned int A0 = cvtpk(p[0], p[1]),  A1 = cvtpk(p[2], p[3]);
    unsigned int B0 = cvtpk(p[4], p[5]),  B1 = cvtpk(p[6], p[7]);
    unsigned int C0 = cvtpk(p[8], p[9]),  C1 = cvtpk(p[10], p[11]);
    unsigned int D0 = cvtpk(p[12], p[13]), D1 = cvtpk(p[14], p[15]);
    unsigned int t0 = __shfl_xor(h ? A0 : B0, 32);
    unsigned int t1 = __shfl_xor(h ? A1 : B1, 32);
    unsigned int t2 = __shfl_xor(h ? C0 : D0, 32);
    unsigned int t3 = __shfl_xor(h ? C1 : D1, 32);
    f0 = mk8(h ? t0 : A0, h ? t1 : A1, h ? B0 : t0, h ? B1 : t1);
    f1 = mk8(h ? t2 : C0, h ? t3 : C1, h ? D0 : t2, h ? D1 : t3);
}

// ---------- flash attention v3: LDS-staged, XOR-swizzled, double-buffered ----
// LDS layout: logical (row r, byte-col c in [0,128)) stored at r*128 + (c ^ ((r&7)<<4)).
// Staged via global_load_lds with pre-swizzled global source (rule #21).
__global__ __launch_bounds__(512, 4) void flash3_kernel(
    const unsigned short* __restrict__ Q,
    const unsigned short* __restrict__ K,
    const unsigned short* __restrict__ VT,
    unsigned short* __restrict__ Oa)
{
    __shared__ __align__(16) char kls[2][8192];
    __shared__ __align__(16) char vls[2][8192];
    const int tid = threadIdx.x, lane = tid & 63, wave = tid >> 6;
    const int h = lane >> 5, ql = lane & 31;
    // XCD-bijective swizzle: all 8 q-tiles of one bh land on one XCD.
    const int bid = blockIdx.x;
    const int bh = (bid & 7) | ((bid >> 6) << 3);
    const int qt = (bid >> 3) & 7;
    const int q0 = qt * 256 + wave * 32;
    const unsigned short* Qb = Q + (size_t)bh * LSEQ * EH;
    const unsigned short* Kb = K + (size_t)bh * LSEQ * EH;
    const unsigned short* Vb = VT + (size_t)bh * EH * LSEQ;

    // staging coords (per thread): row r, linear LDS slot, swizzled global col
    const int sr = tid >> 3;                 // 0..63
    const int scs = (tid & 7) * 16;          // LDS linear byte col
    const int scl = scs ^ ((sr & 7) << 4);   // logical (global) byte col

    // Q B-frags: lane holds Q[q0+ql][e = 16s + 8h + j]
    short8 qf[4];
    #pragma unroll
    for (int s = 0; s < 4; ++s)
        qf[s] = *(const short8*)(Qb + (size_t)(q0 + ql) * EH + s * 16 + h * 8);

    f32x16 o0 = {}, o1 = {};   // O^T accs: e-blocks [0,32), [32,64); col = q = ql
    float m_ = -1e30f, l_ = 0.f;
    const float CEXP = 0.125f * 1.44269504088896f;  // scale * log2(e)

    // prologue: stage tile 0 into buffer 0
    {
        const char* gk = (const char*)(Kb + (size_t)sr * EH) + scl;
        const char* gv = (const char*)(Vb + (size_t)sr * LSEQ) + scl;
        __builtin_amdgcn_global_load_lds(
            (const __attribute__((address_space(1))) void*)gk,
            (__attribute__((address_space(3))) void*)(&kls[0][tid * 16]), 16, 0, 0);
        __builtin_amdgcn_global_load_lds(
            (const __attribute__((address_space(1))) void*)gv,
            (__attribute__((address_space(3))) void*)(&vls[0][tid * 16]), 16, 0, 0);
    }
    __syncthreads();   // drains vmcnt before barrier (compiler-emitted)

    for (int it = 0; it < 32; ++it) {
        const int cur = it & 1;
        const int kt = it * 64;
        // stage next tile into the other buffer (loads fly under this tile's compute)
        if (it + 1 < 32) {
            const int ktn = kt + 64;
            const char* gk = (const char*)(Kb + (size_t)(ktn + sr) * EH) + scl;
            const char* gv = (const char*)(Vb + (size_t)sr * LSEQ + ktn) + scl;
            __builtin_amdgcn_global_load_lds(
                (const __attribute__((address_space(1))) void*)gk,
                (__attribute__((address_space(3))) void*)(&kls[cur ^ 1][tid * 16]), 16, 0, 0);
            __builtin_amdgcn_global_load_lds(
                (const __attribute__((address_space(1))) void*)gv,
                (__attribute__((address_space(3))) void*)(&vls[cur ^ 1][tid * 16]), 16, 0, 0);
        }

        const char* kb = &kls[cur][0];
        const char* vb = &vls[cur][0];

        // S^T = K · Q^T : two 32-kv blocks
        f32x16 s0 = {}, s1 = {};
        __builtin_amdgcn_s_setprio(1);
        #pragma unroll
        for (int s = 0; s < 4; ++s) {
            const int c = s * 32 + h * 16;
            short8 k0 = *(const short8*)(kb + ql * 128 + (c ^ ((ql & 7) << 4)));
            short8 k1 = *(const short8*)(kb + (32 + ql) * 128 + (c ^ ((ql & 7) << 4)));
            s0 = __builtin_amdgcn_mfma_f32_32x32x16_bf16(k0, qf[s], s0, 0, 0, 0);
            s1 = __builtin_amdgcn_mfma_f32_32x32x16_bf16(k1, qf[s], s1, 0, 0, 0);
        }
        __builtin_amdgcn_s_setprio(0);

        // online softmax; lane owns q-row ql, halves combine via shfl_xor(32)
        float a[8];
        #pragma unroll
        for (int i = 0; i < 8; ++i)
            a[i] = fmaxf(fmaxf(s0[i], s0[i + 8]), fmaxf(s1[i], s1[i + 8]));
        #pragma unroll
        for (int i = 0; i < 4; ++i) a[i] = fmaxf(a[i], a[i + 4]);
        float mx = fmaxf(fmaxf(a[0], a[2]), fmaxf(a[1], a[3]));
        mx = fmaxf(mx, __shfl_xor(mx, 32));
        // T13 defer-max: skip rescale when P stays bounded by 2^3
        const int nores = __all((mx - m_) * CEXP <= 3.0f);
        if (!nores) {
            const float mn = fmaxf(m_, mx);
            const float al = exp2f((m_ - mn) * CEXP);
            m_ = mn;
            l_ *= al;
            #pragma unroll
            for (int i = 0; i < 16; ++i) { o0[i] *= al; o1[i] *= al; }
        }
        const float mc = m_ * CEXP;
        #pragma unroll
        for (int i = 0; i < 16; ++i) {
            s0[i] = exp2f(s0[i] * CEXP - mc);
            s1[i] = exp2f(s1[i] * CEXP - mc);
        }
        float bsum[8];
        #pragma unroll
        for (int i = 0; i < 8; ++i)
            bsum[i] = (s0[i] + s0[i + 8]) + (s1[i] + s1[i + 8]);
        #pragma unroll
        for (int i = 0; i < 4; ++i) bsum[i] += bsum[i + 4];
        float sm = (bsum[0] + bsum[1]) + (bsum[2] + bsum[3]);
        sm += __shfl_xor(sm, 32);
        l_ += sm;

        // P -> bf16 B-frags (4 kv-steps of 16)
        short8 pf[4];
        packP(s0, h, pf[0], pf[1]);
        packP(s1, h, pf[2], pf[3]);

        // O^T += V^T · P
        __builtin_amdgcn_s_setprio(1);
        #pragma unroll
        for (int t = 0; t < 4; ++t) {
            const int c = t * 32 + h * 16;
            short8 v0 = *(const short8*)(vb + ql * 128 + (c ^ ((ql & 7) << 4)));
            short8 v1 = *(const short8*)(vb + (32 + ql) * 128 + (c ^ ((ql & 7) << 4)));
            o0 = __builtin_amdgcn_mfma_f32_32x32x16_bf16(v0, pf[t], o0, 0, 0, 0);
            o1 = __builtin_amdgcn_mfma_f32_32x32x16_bf16(v1, pf[t], o1, 0, 0, 0);
        }
        __builtin_amdgcn_s_setprio(0);

        __syncthreads();   // drains vmcnt(0)+lgkmcnt(0): next buffer staged & this one free
    }

    // epilogue: mix layout. l_global = q0+ql; e = (r&3)+8*(r>>2)+4h (+32 for o1)
    const float inv = 1.0f / l_;
    const int b_ = bh >> 4, hd = bh & 15;
    unsigned short* orow = Oa + ((size_t)(b_ * LSEQ + hd * 128 + ((q0 + ql) >> 4)) << 10)
                             + (ql & 15) * 64;
    #pragma unroll
    for (int r = 0; r < 16; r += 2) {
        const int e0 = (r & 3) + 8 * (r >> 2) + 4 * h;
        *(unsigned int*)(orow + e0)      = cvtpk(o0[r] * inv, o0[r + 1] * inv);
        *(unsigned int*)(orow + e0 + 32) = cvtpk(o1[r] * inv, o1[r + 1] * inv);
    }
}

extern "C" void kernel_launch(void* const* d_in, const int* in_sizes, int n_in,
                              void* d_out, int out_size, void* d_ws, size_t ws_size,
                              hipStream_t stream) {
    (void)in_sizes; (void)n_in; (void)out_size; (void)ws_size;
    const float* q  = (const float*)d_in[0];
    const float* k  = (const float*)d_in[1];
    const float* v  = (const float*)d_in[2];
    const float* Wq = (const float*)d_in[3];
    const float* bq = (const float*)d_in[4];
    const float* Wk = (const float*)d_in[5];
    const float* bk = (const float*)d_in[6];
    const float* Wv = (const float*)d_in[7];
    const float* bv = (const float*)d_in[8];
    const float* Wo = (const float*)d_in[9];
    const float* bo = (const float*)d_in[10];

    char* ws = (char*)d_ws;
    const size_t WT = (size_t)1 << 21;   // 2MB per transposed weight
    const size_t QK = (size_t)1 << 24;   // 16MB per bf16 [8192][1024] buffer
    unsigned short* wt_q = (unsigned short*)(ws);
    unsigned short* wt_k = (unsigned short*)(ws + WT);
    unsigned short* wt_v = (unsigned short*)(ws + 2 * WT);
    unsigned short* wt_o = (unsigned short*)(ws + 3 * WT);
    unsigned short* qb   = (unsigned short*)(ws + 4 * WT);            // 16MB
    unsigned short* ab   = (unsigned short*)(ws + 4 * WT + QK);       // 16MB
    unsigned short* vt   = (unsigned short*)(ws + 4 * WT + 2 * QK);   // 16MB (ws total 56MB)
    // K/V bf16 intermediates live in d_out (32MB fp32 buffer, fully
    // overwritten by the final GEMM afterwards -> deterministic).
    unsigned short* kb_  = (unsigned short*)d_out;
    unsigned short* vb   = (unsigned short*)((char*)d_out + QK);

    wconv_kernel<<<dim3(256, 4), 256, 0, stream>>>(Wq, Wk, Wv, Wo, wt_q, wt_k, wt_v, wt_o);
    gemm_kernel<false, true><<<dim3(64, 8), 256, 0, stream>>>(q, wt_q, bq, qb);
    gemm_kernel<false, true><<<dim3(64, 8), 256, 0, stream>>>(k, wt_k, bk, kb_);
    gemm_kernel<false, true><<<dim3(64, 8), 256, 0, stream>>>(v, wt_v, bv, vb);
    vtrans_kernel<<<dim3(2048), 256, 0, stream>>>(vb, vt);
    flash3_kernel<<<dim3(512), 512, 0, stream>>>(qb, kb_, vt, ab);
    gemm_kernel<true, false><<<dim3(64, 8), 256, 0, stream>>>(ab, wt_o, bo, (float*)d_out);
}